// Round 17
// baseline (158373.962 us; speedup 1.0000x reference)
//
#include <hip/hip_runtime.h>
#include <hip/hip_cooperative_groups.h>

namespace cg = cooperative_groups;

constexpr int kB = 64, kS = 2048, kD = 512, kL = 4;
constexpr int HBUF_F = 2 * kL * kB * kD;          // 262144 floats
constexpr int WT_F   = kL * kD * kD;              // 1048576 floats
constexpr size_t NEED_WS = (size_t)(HBUF_F + 2 * WT_F) * 4 + 4096;

// CONFIRMED reference tanh (R15/R16): XLA EmitFastTanh with_fma=true.
__device__ __forceinline__ float tanh_ref(float x0) {
#pragma clang fp contract(off)
  const float kMax = 7.99881172180175781f;
  float xc = fminf(fmaxf(x0, -kMax), kMax);
  float x2 = xc * xc;
  float p = -2.76076847742355e-16f;
  p = fmaf(x2, p, 2.00018790482477e-13f);
  p = fmaf(x2, p, -8.60467152213735e-11f);
  p = fmaf(x2, p, 5.12229709037114e-08f);
  p = fmaf(x2, p, 1.48572235717979e-05f);
  p = fmaf(x2, p, 6.37261928875436e-04f);
  p = fmaf(x2, p, 4.89352455891786e-03f);
  float num = xc * p;
  float q = 1.19825839466702e-06f;
  q = fmaf(x2, q, 1.18534705686654e-04f);
  q = fmaf(x2, q, 2.26843463243900e-03f);
  q = fmaf(x2, q, 4.89352518554385e-03f);
  float r = num / q;
  return (fabsf(x0) < 0.0004f) ? x0 : r;
}

// ---------- prep: zero Hbuf + barrier flags ----------
__global__ void prep_zero(float* __restrict__ Hbuf, unsigned* __restrict__ flags) {
  const int gid = blockIdx.x * blockDim.x + threadIdx.x;
  for (int i = gid; i < HBUF_F; i += gridDim.x * blockDim.x) Hbuf[i] = 0.f;
  if (gid < 260) flags[gid] = 0u;
}

// ---------- prep: Wt[l][j][k] = W[l][k][j] (and U) ----------
__global__ void transpose_wu(const float* __restrict__ W, const float* __restrict__ U,
                             float* __restrict__ Wt, float* __restrict__ Ut) {
  __shared__ float tile[32][33];
  const int z = blockIdx.z;             // 0..3 -> W layer, 4..7 -> U layer
  const float* src = (z < 4) ? W : U;
  float* dst = (z < 4) ? Wt : Ut;
  const int l = z & 3;
  const int k0 = blockIdx.x * 32, j0 = blockIdx.y * 32;
  for (int r = threadIdx.y; r < 32; r += 8)
    tile[r][threadIdx.x] = src[((long)l * kD + (k0 + r)) * kD + j0 + threadIdx.x];
  __syncthreads();
  for (int r = threadIdx.y; r < 32; r += 8)
    dst[((long)l * kD + (j0 + r)) * kD + k0 + threadIdx.x] = tile[threadIdx.x][r];
}

// ---------- lightweight grid barrier (flag tree, no atomic contention) ----------
__device__ __forceinline__ void grid_bar(unsigned* arrive, unsigned* go,
                                         int bid, int tid, unsigned epoch) {
  __syncthreads();
  if (bid == 0) {
    if (tid > 0) {
      while (__hip_atomic_load(&arrive[tid], __ATOMIC_RELAXED,
                               __HIP_MEMORY_SCOPE_AGENT) < epoch) {}
    }
    __syncthreads();
    if (tid == 0) {
      __threadfence();  // wb my writes + inv stale (full agent fence)
      __hip_atomic_store(go, epoch, __ATOMIC_RELEASE, __HIP_MEMORY_SCOPE_AGENT);
    }
    __syncthreads();
  } else {
    if (tid == 0) {
      __threadfence();  // make this block's h-writes visible
      __hip_atomic_store(&arrive[bid], epoch, __ATOMIC_RELEASE,
                         __HIP_MEMORY_SCOPE_AGENT);
      while (__hip_atomic_load(go, __ATOMIC_RELAXED,
                               __HIP_MEMORY_SCOPE_AGENT) < epoch) {}
      __threadfence();  // invalidate stale lines before next step's reads
    }
    __syncthreads();
  }
}

// grid 256 = l(4) x jg(64); block 256: lane b = tid&63, q = tid>>6.
// Thread outputs: (b, j0=jg*8+q) and (b, j1=j0+4). Weights wave-uniform
// (scalar path); activations per-lane contiguous float4 from global.
__global__ __launch_bounds__(256, 1) void rnn_fast(
    const float* __restrict__ x, const float* __restrict__ bias,
    const float* __restrict__ Wt, const float* __restrict__ Ut,
    float* __restrict__ out, float* Hbuf, unsigned* arrive, unsigned* go) {
  const int tid = threadIdx.x, bid = blockIdx.x;
  const int l = bid >> 6, jg = bid & 63;
  const int b = tid & 63, q = tid >> 6;
  const int j0 = jg * 8 + q, j1 = j0 + 4;

  const float* wt0 = Wt + ((long)l * kD + j0) * kD;
  const float* wt1 = Wt + ((long)l * kD + j1) * kD;
  const float* ut0 = Ut + ((long)l * kD + j0) * kD;
  const float* ut1 = Ut + ((long)l * kD + j1) * kD;
  const float bv0 = bias[l * kD + j0];
  const float bv1 = bias[l * kD + j1];

  for (int w = 0; w < kS + kL - 1; ++w) {
    const int t = w - l;
    if (t >= 0 && t < kS) {
      const int cur = w & 1, prv = cur ^ 1;
      const float* irow = (l == 0)
          ? (x + ((long)b * kS + t) * kD)
          : (Hbuf + (((long)prv * kL + (l - 1)) * kB + b) * (long)kD);
      const float* hrow = Hbuf + (((long)prv * kL + l) * kB + b) * (long)kD;

      float dw0, dw1, du0, du1;
      {
#pragma clang fp contract(off)
        dw0 = 0.f; dw1 = 0.f; du0 = 0.f; du1 = 0.f;
#pragma unroll 2
        for (int k = 0; k < kD; k += 4) {
          const float4 iv = *(const float4*)(irow + k);
          const float4 hv = *(const float4*)(hrow + k);
          const float4 w0 = *(const float4*)(wt0 + k);
          const float4 w1 = *(const float4*)(wt1 + k);
          const float4 u0 = *(const float4*)(ut0 + k);
          const float4 u1 = *(const float4*)(ut1 + k);
          dw0 = fmaf(iv.x, w0.x, dw0); dw0 = fmaf(iv.y, w0.y, dw0);
          dw0 = fmaf(iv.z, w0.z, dw0); dw0 = fmaf(iv.w, w0.w, dw0);
          dw1 = fmaf(iv.x, w1.x, dw1); dw1 = fmaf(iv.y, w1.y, dw1);
          dw1 = fmaf(iv.z, w1.z, dw1); dw1 = fmaf(iv.w, w1.w, dw1);
          du0 = fmaf(hv.x, u0.x, du0); du0 = fmaf(hv.y, u0.y, du0);
          du0 = fmaf(hv.z, u0.z, du0); du0 = fmaf(hv.w, u0.w, du0);
          du1 = fmaf(hv.x, u1.x, du1); du1 = fmaf(hv.y, u1.y, du1);
          du1 = fmaf(hv.z, u1.z, du1); du1 = fmaf(hv.w, u1.w, du1);
        }
      }
      float z0, z1;
      {
#pragma clang fp contract(off)
        z0 = (dw0 + du0) + bv0;
        z1 = (dw1 + du1) + bv1;
      }
      const float h0 = tanh_ref(z0);
      const float h1 = tanh_ref(z1);

      float* ho = Hbuf + (((long)cur * kL + l) * kB + b) * (long)kD;
      ho[j0] = h0;
      ho[j1] = h1;
      if (l == kL - 1) {
        float* op = out + ((long)b * kS + t) * kD;
        op[j0] = h0;
        op[j1] = h1;
      }
    }
    grid_bar(arrive, go, bid, tid, (unsigned)(w + 1));
  }
}

// ---------- fallback: R16 kernel verbatim (ws too small for transposed W) ----
__global__ __launch_bounds__(256, 1) void rnn_full(
    const float* __restrict__ x, const float* __restrict__ Wh,
    const float* __restrict__ Uh, const float* __restrict__ bias,
    float* __restrict__ out, float* __restrict__ ws) {
  cg::grid_group grid = cg::this_grid();
  float* Hbuf = ws;
  const int tid = threadIdx.x, bid = blockIdx.x;
  const int l = bid >> 6;
  const int bg = (bid >> 3) & 7;
  const int jg = bid & 7;
  const int jl = tid & 63;
  const int bq = tid >> 6;
  const int j = jg * 64 + jl;
  const int b0 = bg * 8 + bq * 2;
  __shared__ float iS[8][512];
  __shared__ float hS[8][512];
  for (int i = bid * 256 + tid; i < HBUF_F; i += 256 * 256) Hbuf[i] = 0.f;
  grid.sync();
  const float* Wcol = Wh + (long)l * kD * kD + j;
  const float* Ucol = Uh + (long)l * kD * kD + j;
  const float bv = bias[l * kD + j];
  for (int w = 0; w < kS + kL - 1; ++w) {
    const int t = w - l;
    if (t >= 0 && t < kS) {
      const int cur = w & 1, prv = cur ^ 1;
      const float* hbase = Hbuf + (((long)prv * kL + l) * kB + bg * 8) * (long)kD;
      const float* ibase = (l == 0) ? nullptr
          : Hbuf + (((long)prv * kL + (l - 1)) * kB + bg * 8) * (long)kD;
      for (int i = tid; i < 8 * 128; i += 256) {
        const int r = i >> 7, q4 = (i & 127) * 4;
        const float* isrc = (l == 0)
            ? (x + ((long)(bg * 8 + r) * kS + t) * kD + q4)
            : (ibase + (long)r * kD + q4);
        *(float4*)&iS[r][q4] = *(const float4*)isrc;
        *(float4*)&hS[r][q4] = *(const float4*)(hbase + (long)r * kD + q4);
      }
      __syncthreads();
      const int r0 = bq * 2, r1 = r0 + 1;
      float dw0, dw1, du0, du1;
      {
#pragma clang fp contract(off)
        dw0 = 0.f; dw1 = 0.f; du0 = 0.f; du1 = 0.f;
#pragma unroll 4
        for (int k = 0; k < 512; ++k) {
          const float wv = Wcol[(long)k * kD];
          const float uv = Ucol[(long)k * kD];
          dw0 = fmaf(iS[r0][k], wv, dw0);
          dw1 = fmaf(iS[r1][k], wv, dw1);
          du0 = fmaf(hS[r0][k], uv, du0);
          du1 = fmaf(hS[r1][k], uv, du1);
        }
      }
      float z0, z1;
      {
#pragma clang fp contract(off)
        z0 = (dw0 + du0) + bv;
        z1 = (dw1 + du1) + bv;
      }
      const float h0 = tanh_ref(z0);
      const float h1 = tanh_ref(z1);
      float* ho = Hbuf + (((long)cur * kL + l) * kB) * (long)kD;
      ho[(long)b0 * kD + j] = h0;
      ho[(long)(b0 + 1) * kD + j] = h1;
      if (l == kL - 1) {
        out[((long)b0 * kS + t) * kD + j] = h0;
        out[((long)(b0 + 1) * kS + t) * kD + j] = h1;
      }
    }
    grid.sync();
  }
}

extern "C" void kernel_launch(void* const* d_in, const int* in_sizes, int n_in,
                              void* d_out, int out_size, void* d_ws, size_t ws_size,
                              hipStream_t stream) {
  const float* x    = (const float*)d_in[0];
  const float* Wh   = (const float*)d_in[1];
  const float* Uh   = (const float*)d_in[2];
  const float* bias = (const float*)d_in[3];
  float* out = (float*)d_out;
  float* ws  = (float*)d_ws;

  if (ws_size >= NEED_WS) {
    float* Hbuf = ws;
    float* Wt = ws + HBUF_F;
    float* Ut = Wt + WT_F;
    unsigned* flags = (unsigned*)(Ut + WT_F);
    unsigned* arrive = flags;
    unsigned* go = flags + 256;

    prep_zero<<<256, 256, 0, stream>>>(Hbuf, flags);
    transpose_wu<<<dim3(16, 16, 8), dim3(32, 8), 0, stream>>>(Wh, Uh, Wt, Ut);

    void* args[] = {(void*)&x, (void*)&bias, (void*)&Wt, (void*)&Ut,
                    (void*)&out, (void*)&Hbuf, (void*)&arrive, (void*)&go};
    hipLaunchCooperativeKernel((void*)rnn_fast, dim3(256), dim3(256), args, 0,
                               stream);
  } else {
    void* args[] = {(void*)&x, (void*)&Wh, (void*)&Uh, (void*)&bias,
                    (void*)&out, (void*)&ws};
    hipLaunchCooperativeKernel((void*)rnn_full, dim3(256), dim3(256), args, 0,
                               stream);
  }
}

// Round 18
// 65069.910 us; speedup vs baseline: 2.4339x; 2.4339x over previous
//
#include <hip/hip_runtime.h>
#include <hip/hip_cooperative_groups.h>

namespace cg = cooperative_groups;

constexpr int kB = 64, kS = 2048, kD = 512, kL = 4;
constexpr int kR = 8;                                  // ring depth (time slots)
constexpr int RING_F = kR * kL * kB * kD;              // 1048576 floats (4 MB)
constexpr int ZBUF_F = kB * kD;                        // 32768 floats (128 KB)
constexpr int CNT_N  = kL * 8 * kS;                    // 65536 counters
constexpr size_t NEED_WS = (size_t)(RING_F + ZBUF_F + CNT_N) * 4 + 4096;

// CONFIRMED reference tanh (R15/R16): XLA EmitFastTanh with_fma=true.
__device__ __forceinline__ float tanh_ref(float x0) {
#pragma clang fp contract(off)
  const float kMax = 7.99881172180175781f;
  float xc = fminf(fmaxf(x0, -kMax), kMax);
  float x2 = xc * xc;
  float p = -2.76076847742355e-16f;
  p = fmaf(x2, p, 2.00018790482477e-13f);
  p = fmaf(x2, p, -8.60467152213735e-11f);
  p = fmaf(x2, p, 5.12229709037114e-08f);
  p = fmaf(x2, p, 1.48572235717979e-05f);
  p = fmaf(x2, p, 6.37261928875436e-04f);
  p = fmaf(x2, p, 4.89352455891786e-03f);
  float num = xc * p;
  float q = 1.19825839466702e-06f;
  q = fmaf(x2, q, 1.18534705686654e-04f);
  q = fmaf(x2, q, 2.26843463243900e-03f);
  q = fmaf(x2, q, 4.89352518554385e-03f);
  float r = num / q;
  return (fabsf(x0) < 0.0004f) ? x0 : r;
}

__global__ void prep_zero(float* __restrict__ zbuf, unsigned* __restrict__ cnt) {
  const int gid = blockIdx.x * blockDim.x + threadIdx.x;
  for (int i = gid; i < ZBUF_F; i += gridDim.x * blockDim.x) zbuf[i] = 0.f;
  for (int i = gid; i < CNT_N; i += gridDim.x * blockDim.x) cnt[i] = 0u;
}

__device__ __forceinline__ unsigned cnt_ld(const unsigned* p) {
  return __hip_atomic_load(p, __ATOMIC_RELAXED, __HIP_MEMORY_SCOPE_AGENT);
}

// grid 256 = l(4) x bg(8) x jg(8); block 256 = bq(4) x jl(64).
// R16-verbatim compute (bit-exact); sync = per-(l,bg) counters + depth-8 ring.
__global__ __launch_bounds__(256, 1) void rnn_pipe(
    const float* __restrict__ x, const float* __restrict__ Wh,
    const float* __restrict__ Uh, const float* __restrict__ bias,
    float* __restrict__ out, float* __restrict__ ring,
    float* __restrict__ zbuf, unsigned* __restrict__ cnt) {
  const int tid = threadIdx.x, bid = blockIdx.x;
  const int l  = bid >> 6;
  const int bg = (bid >> 3) & 7;
  const int jg = bid & 7;
  const int jl = tid & 63;
  const int bq = tid >> 6;
  const int j  = jg * 64 + jl;
  const int b0 = bg * 8 + bq * 2;

  __shared__ float iS[8][512];
  __shared__ float hS[8][512];

  const float* Wcol = Wh + (long)l * kD * kD + j;
  const float* Ucol = Uh + (long)l * kD * kD + j;
  const float bv = bias[l * kD + j];

  const unsigned* cSibling = cnt + ((long)l * 8 + bg) * kS;        // [t]
  const unsigned* cBelow   = (l > 0) ? cnt + ((long)(l - 1) * 8 + bg) * kS : nullptr;
  const unsigned* cAbove   = (l < kL - 1) ? cnt + ((long)(l + 1) * 8 + bg) * kS : nullptr;
  unsigned* cMine = cnt + ((long)l * 8 + bg) * kS;

  for (int t = 0; t < kS; ++t) {
    // ---- waits: siblings(t-1), below(t), ring back-pressure(above, t-R) ----
    if (tid == 0) {
      if (t > 0)            while (cnt_ld(&cSibling[t - 1]) < 8u) __builtin_amdgcn_s_sleep(1);
      if (l > 0)            while (cnt_ld(&cBelow[t]) < 8u)       __builtin_amdgcn_s_sleep(1);
      if (cAbove && t >= kR) while (cnt_ld(&cAbove[t - kR]) < 8u) __builtin_amdgcn_s_sleep(1);
      __threadfence();  // invalidate stale L1/L2 lines before staging reads
    }
    __syncthreads();

    // ---- stage 8 inp rows + 8 h(t-1) rows into LDS (coalesced) ----
    const int slot  = t & (kR - 1);
    const int slotP = (t - 1) & (kR - 1);
    const float* ibase = (l == 0)
        ? nullptr
        : ring + (((long)slot * kL + (l - 1)) * kB + bg * 8) * (long)kD;
    const float* hbase = (t == 0)
        ? zbuf + (long)(bg * 8) * kD
        : ring + (((long)slotP * kL + l) * kB + bg * 8) * (long)kD;
    for (int i = tid; i < 8 * 128; i += 256) {
      const int r = i >> 7, q4 = (i & 127) * 4;
      const float* isrc = (l == 0)
          ? (x + ((long)(bg * 8 + r) * kS + t) * kD + q4)
          : (ibase + (long)r * kD + q4);
      *(float4*)&iS[r][q4] = *(const float4*)isrc;
      *(float4*)&hS[r][q4] = *(const float4*)(hbase + (long)r * kD + q4);
    }
    __syncthreads();

    // ---- R16-verbatim bit-exact chains ----
    const int r0 = bq * 2, r1 = r0 + 1;
    float dw0, dw1, du0, du1;
    {
#pragma clang fp contract(off)
      dw0 = 0.f; dw1 = 0.f; du0 = 0.f; du1 = 0.f;
#pragma unroll 4
      for (int k = 0; k < 512; ++k) {
        const float wv = Wcol[(long)k * kD];
        const float uv = Ucol[(long)k * kD];
        dw0 = fmaf(iS[r0][k], wv, dw0);
        dw1 = fmaf(iS[r1][k], wv, dw1);
        du0 = fmaf(hS[r0][k], uv, du0);
        du1 = fmaf(hS[r1][k], uv, du1);
      }
    }
    float z0, z1;
    {
#pragma clang fp contract(off)
      z0 = (dw0 + du0) + bv;
      z1 = (dw1 + du1) + bv;
    }
    const float h0 = tanh_ref(z0);
    const float h1 = tanh_ref(z1);

    float* ho = ring + (((long)slot * kL + l) * kB) * (long)kD;
    ho[(long)b0 * kD + j] = h0;
    ho[(long)(b0 + 1) * kD + j] = h1;
    if (l == kL - 1) {
      out[((long)b0 * kS + t) * kD + j] = h0;
      out[((long)(b0 + 1) * kS + t) * kD + j] = h1;
    }

    __syncthreads();  // drains this block's global writes (vmcnt 0)
    if (tid == 0) {
      __threadfence();  // write back to device-visible point
      atomicAdd(&cMine[t], 1u);  // device-scope by default
    }
  }
}

// ---------- fallback: R16 kernel verbatim ----------
__global__ __launch_bounds__(256, 1) void rnn_full(
    const float* __restrict__ x, const float* __restrict__ Wh,
    const float* __restrict__ Uh, const float* __restrict__ bias,
    float* __restrict__ out, float* __restrict__ ws) {
  cg::grid_group grid = cg::this_grid();
  float* Hbuf = ws;
  const int tid = threadIdx.x, bid = blockIdx.x;
  const int l = bid >> 6;
  const int bg = (bid >> 3) & 7;
  const int jg = bid & 7;
  const int jl = tid & 63;
  const int bq = tid >> 6;
  const int j = jg * 64 + jl;
  const int b0 = bg * 8 + bq * 2;
  __shared__ float iS[8][512];
  __shared__ float hS[8][512];
  for (int i = bid * 256 + tid; i < 2 * kL * kB * kD; i += 256 * 256) Hbuf[i] = 0.f;
  grid.sync();
  const float* Wcol = Wh + (long)l * kD * kD + j;
  const float* Ucol = Uh + (long)l * kD * kD + j;
  const float bv = bias[l * kD + j];
  for (int w = 0; w < kS + kL - 1; ++w) {
    const int t = w - l;
    if (t >= 0 && t < kS) {
      const int cur = w & 1, prv = cur ^ 1;
      const float* hbase = Hbuf + (((long)prv * kL + l) * kB + bg * 8) * (long)kD;
      const float* ibase = (l == 0) ? nullptr
          : Hbuf + (((long)prv * kL + (l - 1)) * kB + bg * 8) * (long)kD;
      for (int i = tid; i < 8 * 128; i += 256) {
        const int r = i >> 7, q4 = (i & 127) * 4;
        const float* isrc = (l == 0)
            ? (x + ((long)(bg * 8 + r) * kS + t) * kD + q4)
            : (ibase + (long)r * kD + q4);
        *(float4*)&iS[r][q4] = *(const float4*)isrc;
        *(float4*)&hS[r][q4] = *(const float4*)(hbase + (long)r * kD + q4);
      }
      __syncthreads();
      const int r0 = bq * 2, r1 = r0 + 1;
      float dw0, dw1, du0, du1;
      {
#pragma clang fp contract(off)
        dw0 = 0.f; dw1 = 0.f; du0 = 0.f; du1 = 0.f;
#pragma unroll 4
        for (int k = 0; k < 512; ++k) {
          const float wv = Wcol[(long)k * kD];
          const float uv = Ucol[(long)k * kD];
          dw0 = fmaf(iS[r0][k], wv, dw0);
          dw1 = fmaf(iS[r1][k], wv, dw1);
          du0 = fmaf(hS[r0][k], uv, du0);
          du1 = fmaf(hS[r1][k], uv, du1);
        }
      }
      float z0, z1;
      {
#pragma clang fp contract(off)
        z0 = (dw0 + du0) + bv;
        z1 = (dw1 + du1) + bv;
      }
      const float h0 = tanh_ref(z0);
      const float h1 = tanh_ref(z1);
      float* ho = Hbuf + (((long)cur * kL + l) * kB) * (long)kD;
      ho[(long)b0 * kD + j] = h0;
      ho[(long)(b0 + 1) * kD + j] = h1;
      if (l == kL - 1) {
        out[((long)b0 * kS + t) * kD + j] = h0;
        out[((long)(b0 + 1) * kS + t) * kD + j] = h1;
      }
    }
    grid.sync();
  }
}

extern "C" void kernel_launch(void* const* d_in, const int* in_sizes, int n_in,
                              void* d_out, int out_size, void* d_ws, size_t ws_size,
                              hipStream_t stream) {
  const float* x    = (const float*)d_in[0];
  const float* Wh   = (const float*)d_in[1];
  const float* Uh   = (const float*)d_in[2];
  const float* bias = (const float*)d_in[3];
  float* out = (float*)d_out;
  float* ws  = (float*)d_ws;

  if (ws_size >= NEED_WS) {
    float* ring = ws;
    float* zbuf = ws + RING_F;
    unsigned* cnt = (unsigned*)(zbuf + ZBUF_F);

    prep_zero<<<128, 256, 0, stream>>>(zbuf, cnt);

    void* args[] = {(void*)&x, (void*)&Wh, (void*)&Uh, (void*)&bias,
                    (void*)&out, (void*)&ring, (void*)&zbuf, (void*)&cnt};
    hipLaunchCooperativeKernel((void*)rnn_pipe, dim3(256), dim3(256), args, 0,
                               stream);
  } else {
    void* args[] = {(void*)&x, (void*)&Wh, (void*)&Uh, (void*)&bias,
                    (void*)&out, (void*)&ws};
    hipLaunchCooperativeKernel((void*)rnn_full, dim3(256), dim3(256), args, 0,
                               stream);
  }
}